// Round 2
// baseline (136.032 us; speedup 1.0000x reference)
//
#include <hip/hip_runtime.h>
#include <math.h>

namespace {

constexpr int B_ = 4, N_ = 4, C_ = 64, H_ = 128, W_ = 128;
constexpr int HW_ = H_ * W_;
constexpr float EPS_ = 1e-12f;

// out[:, 4] = ref
__global__ __launch_bounds__(256) void copyref_kernel(const float* __restrict__ ref,
                                                      float* __restrict__ out) {
    int t = blockIdx.x * 256 + threadIdx.x;      // one float4 per thread
    int f = t * 4;
    int b = f / (C_ * HW_);
    int within = f - b * (C_ * HW_);
    float4 v = *reinterpret_cast<const float4*>(ref + (size_t)b * C_ * HW_ + within);
    *reinterpret_cast<float4*>(out + (size_t)(b * 5 + N_) * C_ * HW_ + within) = v;
}

// Main kernel: each thread handles 4 consecutive x pixels for one (b, i, y).
// grid = B*N*(H/8) blocks of 256 threads (32 x-groups * 8 rows).
__global__ __launch_bounds__(256) void localcorr_kernel(const float* __restrict__ nbrs,
                                                        const float* __restrict__ ref,
                                                        float* __restrict__ out) {
    const int blk = blockIdx.x;
    const int ytile = blk & 15;      // H/8 = 16 tiles
    const int bi = blk >> 4;
    const int i = bi & 3;
    const int b = bi >> 2;
    const int tid = (int)threadIdx.x;
    const int xg = tid & 31;         // 32 groups of 4 pixels = 128 = W
    const int yr = tid >> 5;         // 8 rows per block
    const int y = ytile * 8 + yr;
    const int xb = xg * 4;

    // reflect-pad (np 'reflect', pad=1): idx -1 -> 1, idx W -> W-2
    const int ym1 = (y == 0) ? 1 : y - 1;
    const int yp1 = (y == H_ - 1) ? H_ - 2 : y + 1;
    const int xm1 = (xb == 0) ? 1 : xb - 1;
    const int xp4 = (xb + 4 == W_) ? W_ - 2 : xb + 4;

    const int ro0 = ym1 * W_, ro1 = y * W_, ro2 = yp1 * W_;

    const float* __restrict__ nb = nbrs + (size_t)(b * N_ + i) * C_ * HW_;
    const float* __restrict__ rp = ref + (size_t)b * C_ * HW_ + y * W_ + xb;

    float dot[9][4];     // dot[k][j]: raw dot of ref-vec(pixel j) with nbr-vec(k-th neighbor of pixel j)
    float nrm2[3][6];    // squared norms of nbr vectors at 3 rows x 6 cols (xb-1 .. xb+4)
    float ref2[4];       // squared norms of ref vectors at the 4 pixels
#pragma unroll
    for (int k = 0; k < 9; ++k)
#pragma unroll
        for (int j = 0; j < 4; ++j) dot[k][j] = 0.f;
#pragma unroll
    for (int r = 0; r < 3; ++r)
#pragma unroll
        for (int m = 0; m < 6; ++m) nrm2[r][m] = 0.f;
#pragma unroll
    for (int j = 0; j < 4; ++j) ref2[j] = 0.f;

    // ---- pass 1 over channels: raw dots + squared norms ----
    for (int c = 0; c < C_; ++c) {
        const float* pc = nb + c * HW_;
        const float4 rv = *reinterpret_cast<const float4*>(rp + c * HW_);
        const float r4[4] = {rv.x, rv.y, rv.z, rv.w};
#pragma unroll
        for (int j = 0; j < 4; ++j) ref2[j] += r4[j] * r4[j];
        const int ros[3] = {ro0, ro1, ro2};
#pragma unroll
        for (int r = 0; r < 3; ++r) {
            const float* row = pc + ros[r];
            const float4 m4 = *reinterpret_cast<const float4*>(row + xb);
            const float v[6] = {row[xm1], m4.x, m4.y, m4.z, m4.w, row[xp4]};
#pragma unroll
            for (int m = 0; m < 6; ++m) nrm2[r][m] += v[m] * v[m];
#pragma unroll
            for (int dx = 0; dx < 3; ++dx) {
#pragma unroll
                for (int j = 0; j < 4; ++j) dot[r * 3 + dx][j] += r4[j] * v[j + dx];
            }
        }
    }

    // ---- normalize, softmax over 9 neighbors per pixel ----
    float invn[3][6];
#pragma unroll
    for (int r = 0; r < 3; ++r)
#pragma unroll
        for (int m = 0; m < 6; ++m) invn[r][m] = 1.f / fmaxf(sqrtf(nrm2[r][m]), EPS_);

    float wtp[9][4];     // softmax weight * inv-norm of that neighbor (folded)
#pragma unroll
    for (int j = 0; j < 4; ++j) {
        const float invr = 1.f / fmaxf(sqrtf(ref2[j]), EPS_);
        float d[9];
#pragma unroll
        for (int r = 0; r < 3; ++r)
#pragma unroll
            for (int dx = 0; dx < 3; ++dx)
                d[r * 3 + dx] = dot[r * 3 + dx][j] * invr * invn[r][j + dx];
        float mx = d[0];
#pragma unroll
        for (int k = 1; k < 9; ++k) mx = fmaxf(mx, d[k]);
        float e[9], s = 0.f;
#pragma unroll
        for (int k = 0; k < 9; ++k) { e[k] = expf(d[k] - mx); s += e[k]; }
        const float is = 1.f / s;
#pragma unroll
        for (int r = 0; r < 3; ++r)
#pragma unroll
            for (int dx = 0; dx < 3; ++dx)
                wtp[r * 3 + dx][j] = e[r * 3 + dx] * is * invn[r][j + dx];
    }

    // ---- pass 2 over channels: aggregate + wdiff + store ----
    const float* __restrict__ nbb = nbrs + (size_t)b * N_ * C_ * HW_;
    float* __restrict__ op = out + (size_t)(b * 5 + i) * C_ * HW_ + y * W_ + xb;
    for (int c = 0; c < C_; ++c) {
        const float* pc = nb + c * HW_;
        float agg[4] = {0.f, 0.f, 0.f, 0.f};
        float ctr[4] = {0.f, 0.f, 0.f, 0.f};
        const int ros[3] = {ro0, ro1, ro2};
#pragma unroll
        for (int r = 0; r < 3; ++r) {
            const float* row = pc + ros[r];
            const float4 m4 = *reinterpret_cast<const float4*>(row + xb);
            const float v[6] = {row[xm1], m4.x, m4.y, m4.z, m4.w, row[xp4]};
#pragma unroll
            for (int dx = 0; dx < 3; ++dx) {
#pragma unroll
                for (int j = 0; j < 4; ++j) agg[j] += wtp[r * 3 + dx][j] * v[j + dx];
            }
            if (r == 1) {
#pragma unroll
                for (int j = 0; j < 4; ++j) ctr[j] = v[j + 1];
            }
        }
        // mean over the 4 neighbor images at (c, y, xb..xb+3)
        const float4 q0 = *reinterpret_cast<const float4*>(nbb + (size_t)(0 * C_ + c) * HW_ + ro1 + xb);
        const float4 q1 = *reinterpret_cast<const float4*>(nbb + (size_t)(1 * C_ + c) * HW_ + ro1 + xb);
        const float4 q2 = *reinterpret_cast<const float4*>(nbb + (size_t)(2 * C_ + c) * HW_ + ro1 + xb);
        const float4 q3 = *reinterpret_cast<const float4*>(nbb + (size_t)(3 * C_ + c) * HW_ + ro1 + xb);
        const float mn[4] = {0.25f * (q0.x + q1.x + q2.x + q3.x),
                             0.25f * (q0.y + q1.y + q2.y + q3.y),
                             0.25f * (q0.z + q1.z + q2.z + q3.z),
                             0.25f * (q0.w + q1.w + q2.w + q3.w)};
        float o[4];
#pragma unroll
        for (int j = 0; j < 4; ++j) {
            const float dd = ctr[j] - mn[j];
            o[j] = agg[j] * expf(-dd * dd);
        }
        float4 o4; o4.x = o[0]; o4.y = o[1]; o4.z = o[2]; o4.w = o[3];
        *reinterpret_cast<float4*>(op + c * HW_) = o4;
    }
}

}  // namespace

extern "C" void kernel_launch(void* const* d_in, const int* in_sizes, int n_in,
                              void* d_out, int out_size, void* d_ws, size_t ws_size,
                              hipStream_t stream) {
    const float* nbrs = (const float*)d_in[0];
    const float* ref = (const float*)d_in[1];
    float* out = (float*)d_out;

    // slot 4 = ref copy: B*C*HW floats / 4 per thread / 256 per block
    copyref_kernel<<<(B_ * C_ * HW_ / 4) / 256, 256, 0, stream>>>(ref, out);

    // main: B*N*(H/8) blocks
    localcorr_kernel<<<B_ * N_ * (H_ / 8), 256, 0, stream>>>(nbrs, ref, out);
}

// Round 3
// 129.996 us; speedup vs baseline: 1.0464x; 1.0464x over previous
//
#include <hip/hip_runtime.h>
#include <math.h>

namespace {

constexpr int B_ = 4, N_ = 4, C_ = 64, H_ = 128, W_ = 128;
constexpr int HW_ = H_ * W_;

// out[:, 4] = ref
__global__ __launch_bounds__(256) void copyref_kernel(const float* __restrict__ ref,
                                                      float* __restrict__ out) {
    int t = blockIdx.x * 256 + threadIdx.x;      // one float4 per thread
    int f = t * 4;
    int b = f / (C_ * HW_);
    int within = f - b * (C_ * HW_);
    float4 v = *reinterpret_cast<const float4*>(ref + (size_t)b * C_ * HW_ + within);
    *reinterpret_cast<float4*>(out + (size_t)(b * 5 + N_) * C_ * HW_ + within) = v;
}

// Main kernel: lane-quad C-split.
//   thread -> (pixel-group g of 4 consecutive x, channel-chunk q of 16 channels)
//   q = tid & 3  -> the 4 partial reducers of a group are adjacent lanes (shfl_xor width-4 reduce)
//   block = 256 threads = 64 groups = 2 rows; grid = B*N*(H/2) = 1024 blocks.
__global__ __launch_bounds__(256, 4) void localcorr_kernel(const float* __restrict__ nbrs,
                                                           const float* __restrict__ ref,
                                                           float* __restrict__ out) {
    const int blk = blockIdx.x;
    const int ypair = blk & 63;      // H/2 = 64
    const int bi = blk >> 6;
    const int i = bi & 3;
    const int b = bi >> 2;
    const int tid = (int)threadIdx.x;
    const int q = tid & 3;           // channel chunk
    const int g = tid >> 2;          // pixel group 0..63
    const int y = ypair * 2 + (g >> 5);
    const int xb = (g & 31) * 4;
    const int c0 = q * 16;

    // reflect-pad (np 'reflect', pad=1): idx -1 -> 1, idx W -> W-2
    const int ym1 = (y == 0) ? 1 : y - 1;
    const int yp1 = (y == H_ - 1) ? H_ - 2 : y + 1;
    const int xm1 = (xb == 0) ? 1 : xb - 1;
    const int xp4 = (xb + 4 == W_) ? W_ - 2 : xb + 4;

    const int ro0 = ym1 * W_, ro1 = y * W_, ro2 = yp1 * W_;

    const float* __restrict__ nb = nbrs + (size_t)(b * N_ + i) * C_ * HW_;
    const float* __restrict__ rp = ref + (size_t)b * C_ * HW_ + y * W_ + xb;

    float dot[9][4];     // partial dots over this thread's 16 channels
    float nrm2[3][6];    // partial sq-norms, 3 rows x 6 cols (xb-1 .. xb+4)
    float ref2[4];       // partial ref sq-norms
#pragma unroll
    for (int k = 0; k < 9; ++k)
#pragma unroll
        for (int j = 0; j < 4; ++j) dot[k][j] = 0.f;
#pragma unroll
    for (int r = 0; r < 3; ++r)
#pragma unroll
        for (int m = 0; m < 6; ++m) nrm2[r][m] = 0.f;
#pragma unroll
    for (int j = 0; j < 4; ++j) ref2[j] = 0.f;

    // ---- pass 1 over this thread's channels: raw dots + squared norms ----
    for (int cc = 0; cc < 16; ++cc) {
        const int c = c0 + cc;
        const float* pc = nb + c * HW_;
        const float4 rv = *reinterpret_cast<const float4*>(rp + c * HW_);
        const float r4[4] = {rv.x, rv.y, rv.z, rv.w};
#pragma unroll
        for (int j = 0; j < 4; ++j) ref2[j] += r4[j] * r4[j];
        const int ros[3] = {ro0, ro1, ro2};
#pragma unroll
        for (int r = 0; r < 3; ++r) {
            const float* row = pc + ros[r];
            const float4 m4 = *reinterpret_cast<const float4*>(row + xb);
            const float v[6] = {row[xm1], m4.x, m4.y, m4.z, m4.w, row[xp4]};
#pragma unroll
            for (int m = 0; m < 6; ++m) nrm2[r][m] += v[m] * v[m];
#pragma unroll
            for (int dx = 0; dx < 3; ++dx) {
#pragma unroll
                for (int j = 0; j < 4; ++j) dot[r * 3 + dx][j] += r4[j] * v[j + dx];
            }
        }
    }

    // ---- reduce partials across the 4 chunk-lanes (width-4 butterfly) ----
#pragma unroll
    for (int k = 0; k < 9; ++k)
#pragma unroll
        for (int j = 0; j < 4; ++j) {
            float v = dot[k][j];
            v += __shfl_xor(v, 1, 4);
            v += __shfl_xor(v, 2, 4);
            dot[k][j] = v;
        }
#pragma unroll
    for (int r = 0; r < 3; ++r)
#pragma unroll
        for (int m = 0; m < 6; ++m) {
            float v = nrm2[r][m];
            v += __shfl_xor(v, 1, 4);
            v += __shfl_xor(v, 2, 4);
            nrm2[r][m] = v;
        }
#pragma unroll
    for (int j = 0; j < 4; ++j) {
        float v = ref2[j];
        v += __shfl_xor(v, 1, 4);
        v += __shfl_xor(v, 2, 4);
        ref2[j] = v;
    }

    // ---- normalize, softmax over 9 neighbors per pixel (redundant in 4 lanes) ----
    float invn[3][6];
#pragma unroll
    for (int r = 0; r < 3; ++r)
#pragma unroll
        for (int m = 0; m < 6; ++m) invn[r][m] = rsqrtf(fmaxf(nrm2[r][m], 1e-24f));

    float wtp[9][4];     // softmax weight * inv-norm of that neighbor (folded)
#pragma unroll
    for (int j = 0; j < 4; ++j) {
        const float invr = rsqrtf(fmaxf(ref2[j], 1e-24f));
        float d[9];
#pragma unroll
        for (int r = 0; r < 3; ++r)
#pragma unroll
            for (int dx = 0; dx < 3; ++dx)
                d[r * 3 + dx] = dot[r * 3 + dx][j] * invr * invn[r][j + dx];
        float mx = d[0];
#pragma unroll
        for (int k = 1; k < 9; ++k) mx = fmaxf(mx, d[k]);
        float e[9], s = 0.f;
#pragma unroll
        for (int k = 0; k < 9; ++k) { e[k] = __expf(d[k] - mx); s += e[k]; }
        const float is = 1.f / s;
#pragma unroll
        for (int r = 0; r < 3; ++r)
#pragma unroll
            for (int dx = 0; dx < 3; ++dx)
                wtp[r * 3 + dx][j] = e[r * 3 + dx] * is * invn[r][j + dx];
    }

    // ---- pass 2 over this thread's channels: aggregate + wdiff + store ----
    const float* __restrict__ nbb = nbrs + (size_t)b * N_ * C_ * HW_;
    float* __restrict__ op = out + (size_t)(b * 5 + i) * C_ * HW_ + y * W_ + xb;
    for (int cc = 0; cc < 16; ++cc) {
        const int c = c0 + cc;
        const float* pc = nb + c * HW_;
        float agg[4] = {0.f, 0.f, 0.f, 0.f};
        float ctr[4] = {0.f, 0.f, 0.f, 0.f};
        const int ros[3] = {ro0, ro1, ro2};
#pragma unroll
        for (int r = 0; r < 3; ++r) {
            const float* row = pc + ros[r];
            const float4 m4 = *reinterpret_cast<const float4*>(row + xb);
            const float v[6] = {row[xm1], m4.x, m4.y, m4.z, m4.w, row[xp4]};
#pragma unroll
            for (int dx = 0; dx < 3; ++dx) {
#pragma unroll
                for (int j = 0; j < 4; ++j) agg[j] += wtp[r * 3 + dx][j] * v[j + dx];
            }
            if (r == 1) {
#pragma unroll
                for (int j = 0; j < 4; ++j) ctr[j] = v[j + 1];
            }
        }
        // mean over the 4 neighbor images; own image's center row is already in ctr
        float s4[4] = {ctr[0], ctr[1], ctr[2], ctr[3]};
#pragma unroll
        for (int ii = 0; ii < N_; ++ii) {
            if (ii == i) continue;   // block-uniform branch
            const float4 qv = *reinterpret_cast<const float4*>(nbb + (size_t)(ii * C_ + c) * HW_ + ro1 + xb);
            s4[0] += qv.x; s4[1] += qv.y; s4[2] += qv.z; s4[3] += qv.w;
        }
        float o[4];
#pragma unroll
        for (int j = 0; j < 4; ++j) {
            const float dd = ctr[j] - 0.25f * s4[j];
            o[j] = agg[j] * __expf(-dd * dd);
        }
        float4 o4; o4.x = o[0]; o4.y = o[1]; o4.z = o[2]; o4.w = o[3];
        *reinterpret_cast<float4*>(op + c * HW_) = o4;
    }
}

}  // namespace

extern "C" void kernel_launch(void* const* d_in, const int* in_sizes, int n_in,
                              void* d_out, int out_size, void* d_ws, size_t ws_size,
                              hipStream_t stream) {
    const float* nbrs = (const float*)d_in[0];
    const float* ref = (const float*)d_in[1];
    float* out = (float*)d_out;

    // slot 4 = ref copy: B*C*HW floats / 4 per thread / 256 per block
    copyref_kernel<<<(B_ * C_ * HW_ / 4) / 256, 256, 0, stream>>>(ref, out);

    // main: B*N*(H/2) = 1024 blocks
    localcorr_kernel<<<B_ * N_ * (H_ / 2), 256, 0, stream>>>(nbrs, ref, out);
}